// Round 8
// baseline (259.992 us; speedup 1.0000x reference)
//
#include <hip/hip_runtime.h>
#include <hip/hip_bf16.h>

// Bilinear grid sample, align_corners=True, border clamp.
// x: [N, C, H, W] fp32; grid: [N, Ho, Wo, 2] fp32; out: [N, C, Ho, Wo] fp32.
//
// Two-pass via a STATIC __device__ staging buffer (NOT d_ws):
//   Pass 1: transpose x (NCHW fp32) -> g_xt (NHWC bf16). float4 NT loads
//           (x dead after), uint4 CACHED stores (g_xt must stay in L2/L3;
//           NT stores here cost +18us, measured R4).
//   Pass 2: gather + interpolate. 4 independent waves/block, no barriers,
//           DEPTH-3 pipelined 16B/lane gathers (12 loads outstanding beyond
//           the awaited group), LDS transpose, 16B NT stores.
//   Both passes XCD-swizzled: blockIdx b%8 = image n, pinning image n's xt
//   slice to one XCD's L2. Cooperative fusion FAILED under graph capture
//   (R7: kernel never ran) -- keep two plain launches.

constexpr int N = 8, C = 64, H = 256, W = 256, HO = 256, WO = 256;
constexpr int NPIX = N * HO * WO;          // 524288
constexpr int PLANE = H * W;               // 65536

typedef unsigned short ushortv8 __attribute__((ext_vector_type(8)));
typedef float floatx4 __attribute__((ext_vector_type(4)));
typedef unsigned int uintx4 __attribute__((ext_vector_type(4)));

// 67 MB staging buffer, allocated at module load.
__device__ __align__(128) unsigned short g_xt[(size_t)N * PLANE * C];

// ---------------- Pass 1: NCHW fp32 -> NHWC bf16, vectorized ----------------
// Block 256. Tile: 64 channels x 64 pixels. blockIdx swizzled: b%8 = image n.
__global__ __launch_bounds__(256) void transpose_kernel(
    const float* __restrict__ x) {
  __shared__ float tile[64][65];
  int t = threadIdx.x;             // 0..255
  int b = blockIdx.x;              // 8192 = 8 images x 1024 tiles
  int n = b & 7;                   // XCD k <- image k (round-robin dispatch)
  int pixb = (b >> 3) << 6;

  const float* xn = x + (size_t)n * C * PLANE + pixb;
  // load: float4/lane; wave = 4 channels x 64 px, 256B/row coalesced
  int px4 = (t & 15) << 2;
  int c0  = t >> 4;                // 0..15
#pragma unroll
  for (int k = 0; k < 4; ++k) {
    int c = c0 + (k << 4);
    floatx4 v = __builtin_nontemporal_load(
        (const floatx4*)(xn + (size_t)c * PLANE + px4));
    *(floatx4*)&tile[c][px4] = v;
  }
  __syncthreads();

  // store: uint4/lane = 4 words (8 channels) x 1 pixel. Wave covers
  // 8 pixels x 32 words = 1024B contiguous per store instr. CACHED stores:
  // g_xt must remain L2/L3-resident for the gather pass.
  unsigned int* xtw = (unsigned int*)g_xt + ((size_t)(n * PLANE + pixb)) * 32;
  int chq = (t & 7) << 2;          // word offset within pixel (4 words = 8 ch)
  int chb = chq << 1;              // first channel
#pragma unroll
  for (int k = 0; k < 2; ++k) {
    int p = (k << 5) + (t >> 3);   // pixel within tile
    uintx4 wv;
#pragma unroll
    for (int j = 0; j < 4; ++j) {
      float f0 = tile[chb + 2 * j][p];
      float f1 = tile[chb + 2 * j + 1][p];
      __hip_bfloat162 h2 = __float22bfloat162_rn(make_float2(f0, f1));
      unsigned int w;
      __builtin_memcpy(&w, &h2, 4);  // low half = f0 (even channel)
      wv[j] = w;
    }
    *(uintx4*)(xtw + (size_t)p * 32 + chq) = wv;
  }
}

// ---------------- Pass 2: 4 independent waves / block, depth-3 pipeline ----------------
__global__ __launch_bounds__(256, 4) void sample_kernel(
    const float* __restrict__ grid, float* __restrict__ out) {
  // per-wave private half-tile: [channel][pixel-in-half] (+1 pad)
  __shared__ float tile[4][64][33];

  int tid  = threadIdx.x;
  int wid  = tid >> 6;
  int lane = tid & 63;
  int b    = blockIdx.x;                     // 2048 = 8 images x 256 blocks
  int n    = b & 7;                          // XCD k <- image k
  int pixb = (n << 16) + ((b >> 3) << 8) + (wid << 6);
  int p_idx = pixb + lane;

  // --- per-lane own-pixel params (kept in registers, broadcast via shfl) ---
  float2 g = ((const float2*)grid)[p_idx];
  float ix = (g.x + 1.0f) * 0.5f * (float)(W - 1);
  float iy = (g.y + 1.0f) * 0.5f * (float)(H - 1);
  float x0f = floorf(ix), y0f = floorf(iy);
  float fx = ix - x0f, fy = iy - y0f;
  float cx0 = fminf(fmaxf(x0f,        0.f), (float)(W - 1));
  float cx1 = fminf(fmaxf(x0f + 1.f,  0.f), (float)(W - 1));
  float cy0 = fminf(fmaxf(y0f,        0.f), (float)(H - 1));
  float cy1 = fminf(fmaxf(y0f + 1.f,  0.f), (float)(H - 1));
  int x0 = (int)cx0, x1 = (int)cx1, y0 = (int)cy0, y1 = (int)cy1;
  int xl = min(x0, W - 2), yl = min(y0, H - 2);
  float wx0 = 1.f - fx, wx1 = fx, wy0 = 1.f - fy, wy1 = fy;
  // fold border clamp into weights on the fixed 2x2 footprint at (yl, xl)
  float wxl = (x0 == xl ? wx0 : 0.f) + (x1 == xl ? wx1 : 0.f);
  float wxh = (x0 == xl + 1 ? wx0 : 0.f) + (x1 == xl + 1 ? wx1 : 0.f);
  float wyl = (y0 == yl ? wy0 : 0.f) + (y1 == yl ? wy1 : 0.f);
  float wyh = (y0 == yl + 1 ? wy0 : 0.f) + (y1 == yl + 1 ? wy1 : 0.f);
  float w00 = wyl * wxl, w01 = wyl * wxh, w10 = wyh * wxl, w11 = wyh * wxh;
  int bs = ((n << 16) | (yl << 8) | xl) << 6;  // bf16-element index into g_xt

  int ps    = lane >> 3;           // pixel-sub 0..7 within a group
  int chunk = lane & 7;            // channel chunk (8 channels each)
  const unsigned short* xtc = g_xt + (chunk << 3);
  float (*tl)[33] = tile[wid];

  int prow = pixb & (PLANE - 1);
  float* outn = out + (size_t)n * C * PLANE + prow;

  // --- depth-3 pipelined gather: 8 groups of 8 pixels, 4 register slots ---
  ushortv8 A[4][4];  // [slot][corner], slot = g & 3, statically indexed

#define ISSUE(gg, slot)                                                        \
  {                                                                            \
    int p = ((gg) << 3) + ps;                                                  \
    int bsp = __shfl(bs, p);                                                   \
    const ushortv8* src = (const ushortv8*)(xtc + bsp);                        \
    A[slot][0] = src[0];                                                       \
    A[slot][1] = src[C / 8];                                                   \
    A[slot][2] = src[(C * W) / 8];                                             \
    A[slot][3] = src[(C * W + C) / 8];                                         \
  }

  ISSUE(0, 0)
  ISSUE(1, 1)
  ISSUE(2, 2)

#pragma unroll
  for (int gq = 0; gq < 8; ++gq) {
    if (gq + 3 < 8) {
      const int sl = (gq + 3) & 3;   // != gq&3, so no conflict with consume
      ISSUE(gq + 3, sl)
    }
    // --- interpolate group gq ---
    {
      const int sl = gq & 3;
      int p = (gq << 3) + ps;
      float wa = __shfl(w00, p), wb = __shfl(w01, p);
      float wc = __shfl(w10, p), wd = __shfl(w11, p);
      int ph = ((gq & 3) << 3) + ps;   // pixel within half
#pragma unroll
      for (int jp = 0; jp < 4; ++jp) {
        unsigned int ua = ((unsigned int*)&A[sl][0])[jp];
        unsigned int ub = ((unsigned int*)&A[sl][1])[jp];
        unsigned int uc = ((unsigned int*)&A[sl][2])[jp];
        unsigned int ud = ((unsigned int*)&A[sl][3])[jp];
        float a0 = __uint_as_float(ua << 16), a1 = __uint_as_float(ua & 0xffff0000u);
        float b0 = __uint_as_float(ub << 16), b1 = __uint_as_float(ub & 0xffff0000u);
        float c0 = __uint_as_float(uc << 16), c1 = __uint_as_float(uc & 0xffff0000u);
        float d0 = __uint_as_float(ud << 16), d1 = __uint_as_float(ud & 0xffff0000u);
        float r0 = a0 * wa + b0 * wb + c0 * wc + d0 * wd;
        float r1 = a1 * wa + b1 * wb + c1 * wc + d1 * wd;
        int ch = (chunk << 3) + (jp << 1);
        // bank = (8*chunk + 2jp + ph) mod 32 -> 2 lanes/bank (free)
        tl[ch][ph]     = r0;
        tl[ch + 1][ph] = r1;
      }
    }
    // --- writeback a completed half (32 px): b128 LDS reads + 16B stores ---
    if ((gq & 3) == 3) {
      int h = gq >> 2;
      int cs = lane >> 3;          // channel-sub 0..7
      int q  = lane & 7;           // pixel-quad 0..7
#pragma unroll
      for (int k = 0; k < 8; ++k) {
        int c = (k << 3) + cs;
        floatx4 v = *(floatx4*)&tl[c][q << 2];
        __builtin_nontemporal_store(
            v, (floatx4*)(outn + (size_t)c * PLANE + (h << 5) + (q << 2)));
      }
    }
  }
#undef ISSUE
}

extern "C" void kernel_launch(void* const* d_in, const int* in_sizes, int n_in,
                              void* d_out, int out_size, void* d_ws, size_t ws_size,
                              hipStream_t stream) {
  const float* x    = (const float*)d_in[0];
  const float* grid = (const float*)d_in[1];
  float* out        = (float*)d_out;
  (void)d_ws; (void)ws_size;  // workspace unused (harness poison-fills anyway)

  transpose_kernel<<<N * PLANE / 64, 256, 0, stream>>>(x);
  sample_kernel<<<NPIX / 256, 256, 0, stream>>>(grid, out);
}